// Round 1
// baseline (91.531 us; speedup 1.0000x reference)
//
#include <hip/hip_runtime.h>
#include <math.h>

#define BB 4
#define TT 1024
#define FF 256
#define UU 32
#define HALF_W 32      // ATT_WIDTH/2
#define WMAX 64
#define RB 8           // rows per qk block
#define TCH 16         // t rows per attn block
#define NS_MAX 80      // union window <= TCH + 63 = 79

// fast tanh: 1 - 2/(exp(2x)+1); ~1e-6 abs err, well under threshold.
__device__ __forceinline__ float fast_tanh(float x) {
    float e = __expf(2.0f * x);
    return 1.0f - 2.0f / (e + 1.0f);
}

// ---------------------------------------------------------------------------
// Kernel A (unchanged): q'[row,u] = x[row]·Wt[:,u] + bh[u] ; k[row,u] = x[row]·Wx[:,u]
// ---------------------------------------------------------------------------
__global__ __launch_bounds__(256) void qk_kernel(
    const float* __restrict__ x, const float* __restrict__ Wt,
    const float* __restrict__ Wx, const float* __restrict__ bh,
    float* __restrict__ qbuf, float* __restrict__ kbuf) {
    int row0 = blockIdx.x * RB;
    int tid = threadIdx.x;
    __shared__ float xs[RB][FF + 4];
    {
        const float4* src = (const float4*)(x + (size_t)row0 * FF);
#pragma unroll
        for (int i = 0; i < 2; ++i) {
            int p = tid + i * 256;            // float4 index, 0..511
            int r = p >> 6;
            int c = p & 63;
            *(float4*)&xs[r][c * 4] = src[p];
        }
    }
    __syncthreads();

    int r    = tid >> 5;          // 0..7
    int sub  = tid & 31;
    int half = sub >> 4;          // 0=q, 1=k
    int fh   = (sub >> 2) & 3;    // interleaved f-chunk id
    int ug   = (sub & 3) * 8;     // u offset
    const float* __restrict__ W = half ? Wx : Wt;
    const float* __restrict__ xr = xs[r];

    float acc[8] = {0.f, 0.f, 0.f, 0.f, 0.f, 0.f, 0.f, 0.f};
#pragma unroll 4
    for (int it = 0; it < 16; ++it) {
        int f = 4 * fh + 16 * it;
        float4 x4 = *(const float4*)&xr[f];
#pragma unroll
        for (int j = 0; j < 4; ++j) {
            const float4* wp = (const float4*)(W + (size_t)(f + j) * UU + ug);
            float4 w0 = wp[0];
            float4 w1 = wp[1];
            float xv = (j == 0) ? x4.x : (j == 1) ? x4.y : (j == 2) ? x4.z : x4.w;
            acc[0] = fmaf(xv, w0.x, acc[0]);
            acc[1] = fmaf(xv, w0.y, acc[1]);
            acc[2] = fmaf(xv, w0.z, acc[2]);
            acc[3] = fmaf(xv, w0.w, acc[3]);
            acc[4] = fmaf(xv, w1.x, acc[4]);
            acc[5] = fmaf(xv, w1.y, acc[5]);
            acc[6] = fmaf(xv, w1.z, acc[6]);
            acc[7] = fmaf(xv, w1.w, acc[7]);
        }
    }
#pragma unroll
    for (int i = 0; i < 8; ++i) {
        acc[i] += __shfl_xor(acc[i], 4);
        acc[i] += __shfl_xor(acc[i], 8);
    }
    if (fh == 0) {
        int row = row0 + r;
        if (half == 0) {
            float4 b0 = *(const float4*)&bh[ug];
            float4 b1 = *(const float4*)&bh[ug + 4];
            float4 o0 = {acc[0] + b0.x, acc[1] + b0.y, acc[2] + b0.z, acc[3] + b0.w};
            float4 o1 = {acc[4] + b1.x, acc[5] + b1.y, acc[6] + b1.z, acc[7] + b1.w};
            *(float4*)&qbuf[(size_t)row * UU + ug]     = o0;
            *(float4*)&qbuf[(size_t)row * UU + ug + 4] = o1;
        } else {
            float4 o0 = {acc[0], acc[1], acc[2], acc[3]};
            float4 o1 = {acc[4], acc[5], acc[6], acc[7]};
            *(float4*)&kbuf[(size_t)row * UU + ug]     = o0;
            *(float4*)&kbuf[(size_t)row * UU + ug + 4] = o1;
        }
    }
}

// ---------------------------------------------------------------------------
// Kernel B v2: one block per (b, 16-row t-chunk). Grid = 4*64 = 256 blocks.
//   phase 1: stage k union-window (<=79 rows, pad 33: conflict-free reads),
//            q tile, wa; zero a_sh.
//   phase 2: logits+softmax fused per wave: lane = window slot j (64 slots =
//            64 lanes), full-wave shfl reduce, write a into absolute-s slot.
//            Out-of-range s -> e=-1e30 -> a==0 exactly. Unwritten union
//            slots stay 0 from the pre-zero.
//   phase 3: PV: wave owns 4 contiguous rows, lane owns one float4 feature
//            chunk; loop wave's own s-window; no cross-wave reduction.
// ---------------------------------------------------------------------------
__global__ __launch_bounds__(256) void attn2_kernel(
    const float* __restrict__ x, const float* __restrict__ qbuf,
    const float* __restrict__ kbuf, const float* __restrict__ Wa,
    const float* __restrict__ ba, float* __restrict__ out) {
    int blk  = blockIdx.x;           // b * (T/TCH) + chunk
    int b    = blk >> 6;             // T/TCH = 64
    int t0   = (blk & 63) * TCH;
    int tid  = threadIdx.x;
    int lane = tid & 63;
    int w    = tid >> 6;             // wave id 0..3

    int bs0 = max(0, t0 - HALF_W);
    int bs1 = min(TT, t0 + TCH - 1 + HALF_W);   // exclusive
    int NS  = bs1 - bs0;                        // <= 79

    __shared__ float k_sh[NS_MAX][UU + 1];      // pad 33 -> bank (r+u)%32
    __shared__ float q_sh[TCH][UU];
    __shared__ float wa_sh[UU];
    __shared__ float a_sh[TCH][NS_MAX];         // absolute-s index (s - bs0)

    // ---- phase 1: staging ----
    for (int p = tid; p < NS * 8; p += 256) {   // k: float4 loads, scalar stores
        int r  = p >> 3;
        int u4 = (p & 7) * 4;
        float4 v = *(const float4*)&kbuf[(size_t)(b * TT + bs0 + r) * UU + u4];
        k_sh[r][u4 + 0] = v.x;
        k_sh[r][u4 + 1] = v.y;
        k_sh[r][u4 + 2] = v.z;
        k_sh[r][u4 + 3] = v.w;
    }
    if (tid < TCH * 8) {                        // q: 128 float4s
        int r  = tid >> 3;
        int u4 = (tid & 7) * 4;
        float4 v = *(const float4*)&qbuf[(size_t)(b * TT + t0 + r) * UU + u4];
        *(float4*)&q_sh[r][u4] = v;
    }
    if (tid < UU) wa_sh[tid] = Wa[tid];
    for (int p = tid; p < TCH * NS_MAX; p += 256) ((float*)a_sh)[p] = 0.f;
    float ba0 = ba[0];
    __syncthreads();

    // ---- phase 2: logits + softmax, one full wave per row ----
#pragma unroll
    for (int i = 0; i < 4; ++i) {
        int tl = w + 4 * i;               // local row 0..15 (uniform per wave)
        int tg = t0 + tl;                 // global t
        int s  = tg - HALF_W + lane;      // this lane's source position
        float e = -1e30f;
        if (s >= 0 && s < TT) {
            int kr = s - bs0;             // consecutive per lane: conflict-free
            float acc = 0.f;
#pragma unroll
            for (int u = 0; u < UU; ++u)
                acc += fast_tanh(q_sh[tl][u] + k_sh[kr][u]) * wa_sh[u];
            e = acc + ba0;
        }
        float m = e;
#pragma unroll
        for (int off = 1; off < 64; off <<= 1) m = fmaxf(m, __shfl_xor(m, off));
        float p = __expf(e - m);
        float sum = p;
#pragma unroll
        for (int off = 1; off < 64; off <<= 1) sum += __shfl_xor(sum, off);
        if (s >= 0 && s < TT) a_sh[tl][s - bs0] = p / sum;
    }
    __syncthreads();

    // ---- phase 3: PV — wave w owns rows tg0..tg0+3, lane owns feature quad ----
    int tg0 = t0 + 4 * w;
    int sw0 = max(0, tg0 - HALF_W);
    int sw1 = min(TT, tg0 + 3 + HALF_W);        // exclusive
    const float4* __restrict__ xb = (const float4*)(x + (size_t)b * TT * FF);
    const float* __restrict__ ar0 = a_sh[4 * w + 0];
    const float* __restrict__ ar1 = a_sh[4 * w + 1];
    const float* __restrict__ ar2 = a_sh[4 * w + 2];
    const float* __restrict__ ar3 = a_sh[4 * w + 3];
    float4 acc0 = {0.f, 0.f, 0.f, 0.f};
    float4 acc1 = acc0, acc2 = acc0, acc3 = acc0;
#pragma unroll 4
    for (int s = sw0; s < sw1; ++s) {
        float4 xv = xb[(size_t)s * (FF / 4) + lane];
        int so = s - bs0;
        float av0 = ar0[so], av1 = ar1[so], av2 = ar2[so], av3 = ar3[so];
        acc0.x = fmaf(av0, xv.x, acc0.x);
        acc0.y = fmaf(av0, xv.y, acc0.y);
        acc0.z = fmaf(av0, xv.z, acc0.z);
        acc0.w = fmaf(av0, xv.w, acc0.w);
        acc1.x = fmaf(av1, xv.x, acc1.x);
        acc1.y = fmaf(av1, xv.y, acc1.y);
        acc1.z = fmaf(av1, xv.z, acc1.z);
        acc1.w = fmaf(av1, xv.w, acc1.w);
        acc2.x = fmaf(av2, xv.x, acc2.x);
        acc2.y = fmaf(av2, xv.y, acc2.y);
        acc2.z = fmaf(av2, xv.z, acc2.z);
        acc2.w = fmaf(av2, xv.w, acc2.w);
        acc3.x = fmaf(av3, xv.x, acc3.x);
        acc3.y = fmaf(av3, xv.y, acc3.y);
        acc3.z = fmaf(av3, xv.z, acc3.z);
        acc3.w = fmaf(av3, xv.w, acc3.w);
    }
    float4* ob = (float4*)(out + (size_t)(b * TT + tg0) * FF);
    ob[0 * (FF / 4) + lane] = acc0;
    ob[1 * (FF / 4) + lane] = acc1;
    ob[2 * (FF / 4) + lane] = acc2;
    ob[3 * (FF / 4) + lane] = acc3;
}

// ---------------------------------------------------------------------------
// Fallback (only if ws too small): fully fused, recomputes k per block.
// ---------------------------------------------------------------------------
__global__ __launch_bounds__(256) void fused_kernel(
    const float* __restrict__ x, const float* __restrict__ Wt,
    const float* __restrict__ Wx, const float* __restrict__ bh,
    const float* __restrict__ Wa, const float* __restrict__ ba,
    float* __restrict__ out) {
    int row = blockIdx.x;
    int t = row & (TT - 1);
    int b = row >> 10;
    int tid = threadIdx.x;
    int s0 = max(0, t - HALF_W);
    int s1 = min(TT, t + HALF_W);
    int W_ = s1 - s0;

    __shared__ float ks[WMAX * UU];   // 8 KB
    __shared__ float q_sh[UU];
    __shared__ float wa_sh[UU];
    __shared__ float e_sh[WMAX];
    __shared__ float a_sh[WMAX];

    if (tid < UU) {
        const float* xr = x + (size_t)row * FF;
        float acc = 0.f;
        for (int f = 0; f < FF; ++f) acc = fmaf(xr[f], Wt[f * UU + tid], acc);
        q_sh[tid]  = acc + bh[tid];
        wa_sh[tid] = Wa[tid];
    }
    for (int p = tid; p < W_ * UU; p += 256) {
        int sl = p >> 5, u = p & 31;
        const float* xr = x + (size_t)(b * TT + s0 + sl) * FF;
        float acc = 0.f;
        for (int f = 0; f < FF; ++f) acc = fmaf(xr[f], Wx[f * UU + u], acc);
        ks[p] = acc;
    }
    __syncthreads();

    int sl = tid >> 2;
    int j  = tid & 3;
    float partial = 0.f;
    if (sl < W_) {
#pragma unroll
        for (int uu = 0; uu < 8; ++uu) {
            int u = j * 8 + uu;
            partial += fast_tanh(q_sh[u] + ks[sl * UU + u]) * wa_sh[u];
        }
    }
    partial += __shfl_xor(partial, 1);
    partial += __shfl_xor(partial, 2);
    if (j == 0) e_sh[sl] = (sl < W_) ? partial + ba[0] : -1e30f;
    __syncthreads();

    if (tid < 64) {
        float e = e_sh[tid];
        float m = e;
#pragma unroll
        for (int off = 1; off < 64; off <<= 1) m = fmaxf(m, __shfl_xor(m, off));
        float p = __expf(e - m);
        float sum = p;
#pragma unroll
        for (int off = 1; off < 64; off <<= 1) sum += __shfl_xor(sum, off);
        a_sh[tid] = p / sum;
    }
    __syncthreads();

    float acc = 0.f;
    const float* xb = x + (size_t)(b * TT + s0) * FF + tid;
    for (int k2 = 0; k2 < W_; ++k2)
        acc = fmaf(a_sh[k2], xb[(size_t)k2 * FF], acc);
    out[(size_t)row * FF + tid] = acc;
}

extern "C" void kernel_launch(void* const* d_in, const int* in_sizes, int n_in,
                              void* d_out, int out_size, void* d_ws, size_t ws_size,
                              hipStream_t stream) {
    const float* x  = (const float*)d_in[0];
    const float* Wt = (const float*)d_in[1];
    const float* Wx = (const float*)d_in[2];
    const float* bh = (const float*)d_in[3];
    const float* Wa = (const float*)d_in[4];
    const float* ba = (const float*)d_in[5];
    float* out = (float*)d_out;

    const size_t need = (size_t)2 * BB * TT * UU * sizeof(float);   // 1 MiB
    if (ws_size >= need) {
        float* qbuf = (float*)d_ws;
        float* kbuf = qbuf + (size_t)BB * TT * UU;
        qk_kernel<<<BB * TT / RB, 256, 0, stream>>>(x, Wt, Wx, bh, qbuf, kbuf);
        attn2_kernel<<<BB * (TT / TCH), 256, 0, stream>>>(x, qbuf, kbuf, Wa, ba, out);
    } else {
        fused_kernel<<<BB * TT, 256, 0, stream>>>(x, Wt, Wx, bh, Wa, ba, out);
    }
}

// Round 2
// 88.473 us; speedup vs baseline: 1.0346x; 1.0346x over previous
//
#include <hip/hip_runtime.h>
#include <math.h>

#define BB 4
#define TT 1024
#define FF 256
#define UU 32
#define HALF_W 32      // ATT_WIDTH/2
#define WMAX 64
#define RB 8           // rows per qk block
#define TCH 8          // t rows per attn block (512 blocks = 2/CU)
#define NS_MAX 72      // union window <= TCH + 63 = 71

// fast tanh: 1 - 2/(exp(2x)+1); ~1e-6 abs err, well under threshold.
__device__ __forceinline__ float fast_tanh(float x) {
    float e = __expf(2.0f * x);
    return 1.0f - 2.0f / (e + 1.0f);
}

// ---------------------------------------------------------------------------
// Kernel A v2: q'[row,u] = x[row]·Wt[:,u] + bh[u] ; k[row,u] = x[row]·Wx[:,u]
// Re-partitioned so each WAVE owns a disjoint 8-u slice (ug = wave*8):
// per-wave W traffic = 16 KB (8 lanes broadcast/address), block total = 64 KB
// = Wt+Wx read exactly once (was 4x). xs pad-1 rows -> <=2-way LDS aliasing
// (free). Reduce over fh via shfl_xor 16/32 (fh = lane bits 4..5).
// ---------------------------------------------------------------------------
__global__ __launch_bounds__(256) void qk_kernel(
    const float* __restrict__ x, const float* __restrict__ Wt,
    const float* __restrict__ Wx, const float* __restrict__ bh,
    float* __restrict__ qbuf, float* __restrict__ kbuf) {
    int row0 = blockIdx.x * RB;
    int tid = threadIdx.x;
    __shared__ float xs[RB][FF + 1];   // row stride 257: bank key r+4fh, <=2-way
    {
        const float4* src = (const float4*)(x + (size_t)row0 * FF);
#pragma unroll
        for (int i = 0; i < 2; ++i) {
            int p = tid + i * 256;            // float4 index, 0..511
            int r = p >> 6;
            int c = (p & 63) * 4;
            float4 v = src[p];
            xs[r][c + 0] = v.x;
            xs[r][c + 1] = v.y;
            xs[r][c + 2] = v.z;
            xs[r][c + 3] = v.w;
        }
    }
    __syncthreads();

    int lane = tid & 63;
    int w    = tid >> 6;          // wave id 0..3
    int r    = lane & 7;          // row within block
    int half = (lane >> 3) & 1;   // 0=q, 1=k
    int fh   = lane >> 4;         // f-chunk id 0..3
    int ug   = w * 8;             // this wave's u slice
    const float* __restrict__ W = half ? Wx : Wt;
    const float* __restrict__ xr = xs[r];

    float acc[8] = {0.f, 0.f, 0.f, 0.f, 0.f, 0.f, 0.f, 0.f};
#pragma unroll 4
    for (int it = 0; it < 16; ++it) {
        int f = 4 * fh + 16 * it;
        float xv0 = xr[f + 0];
        float xv1 = xr[f + 1];
        float xv2 = xr[f + 2];
        float xv3 = xr[f + 3];
#pragma unroll
        for (int j = 0; j < 4; ++j) {
            const float4* wp = (const float4*)(W + (size_t)(f + j) * UU + ug);
            float4 w0 = wp[0];
            float4 w1 = wp[1];
            float xv = (j == 0) ? xv0 : (j == 1) ? xv1 : (j == 2) ? xv2 : xv3;
            acc[0] = fmaf(xv, w0.x, acc[0]);
            acc[1] = fmaf(xv, w0.y, acc[1]);
            acc[2] = fmaf(xv, w0.z, acc[2]);
            acc[3] = fmaf(xv, w0.w, acc[3]);
            acc[4] = fmaf(xv, w1.x, acc[4]);
            acc[5] = fmaf(xv, w1.y, acc[5]);
            acc[6] = fmaf(xv, w1.z, acc[6]);
            acc[7] = fmaf(xv, w1.w, acc[7]);
        }
    }
    // reduce the 4 fh partials: fh lives in lane bits 4..5
#pragma unroll
    for (int i = 0; i < 8; ++i) {
        acc[i] += __shfl_xor(acc[i], 16);
        acc[i] += __shfl_xor(acc[i], 32);
    }
    if (fh == 0) {                // lanes 0..15: (r, half) complete results
        int row = row0 + r;
        if (half == 0) {
            float4 b0 = *(const float4*)&bh[ug];
            float4 b1 = *(const float4*)&bh[ug + 4];
            float4 o0 = {acc[0] + b0.x, acc[1] + b0.y, acc[2] + b0.z, acc[3] + b0.w};
            float4 o1 = {acc[4] + b1.x, acc[5] + b1.y, acc[6] + b1.z, acc[7] + b1.w};
            *(float4*)&qbuf[(size_t)row * UU + ug]     = o0;
            *(float4*)&qbuf[(size_t)row * UU + ug + 4] = o1;
        } else {
            float4 o0 = {acc[0], acc[1], acc[2], acc[3]};
            float4 o1 = {acc[4], acc[5], acc[6], acc[7]};
            *(float4*)&kbuf[(size_t)row * UU + ug]     = o0;
            *(float4*)&kbuf[(size_t)row * UU + ug + 4] = o1;
        }
    }
}

// ---------------------------------------------------------------------------
// Kernel B v3: one block per (b, 8-row t-chunk). Grid = 4*128 = 512 blocks
// (2 blocks/CU -> 2 waves/SIMD latency hiding; v2's 1 block/CU was fully
// latency-exposed).
//   phase 1: stage k union-window (<=71 rows, pad 33: 2-way/free), q tile,
//            wa; zero a_sh.
//   phase 2: logits+softmax per wave: lane = window slot (64 slots = 64
//            lanes), full-wave shfl reduce, write a into absolute-s slot.
//            Out-of-range s -> e=-1e30 -> a==0 exactly; unwritten union
//            slots stay 0 from the pre-zero.
//   phase 3: wave owns 2 contiguous rows, lane owns one float4 feature
//            chunk; loop the wave's own s-window; no cross-wave reduction.
// ---------------------------------------------------------------------------
__global__ __launch_bounds__(256) void attn2_kernel(
    const float* __restrict__ x, const float* __restrict__ qbuf,
    const float* __restrict__ kbuf, const float* __restrict__ Wa,
    const float* __restrict__ ba, float* __restrict__ out) {
    int blk  = blockIdx.x;           // b * (T/TCH) + chunk
    int b    = blk >> 7;             // T/TCH = 128
    int t0   = (blk & 127) * TCH;
    int tid  = threadIdx.x;
    int lane = tid & 63;
    int w    = tid >> 6;             // wave id 0..3

    int bs0 = max(0, t0 - HALF_W);
    int bs1 = min(TT, t0 + TCH - 1 + HALF_W);   // exclusive
    int NS  = bs1 - bs0;                        // <= 71

    __shared__ float k_sh[NS_MAX][UU + 1];      // pad 33 -> bank (r+u)%32
    __shared__ float q_sh[TCH][UU];
    __shared__ float wa_sh[UU];
    __shared__ float a_sh[TCH][NS_MAX];         // absolute-s index (s - bs0)

    // ---- phase 1: staging ----
    for (int p = tid; p < NS * 8; p += 256) {   // k: float4 loads, scalar stores
        int r  = p >> 3;
        int u4 = (p & 7) * 4;
        float4 v = *(const float4*)&kbuf[(size_t)(b * TT + bs0 + r) * UU + u4];
        k_sh[r][u4 + 0] = v.x;
        k_sh[r][u4 + 1] = v.y;
        k_sh[r][u4 + 2] = v.z;
        k_sh[r][u4 + 3] = v.w;
    }
    if (tid < TCH * 8) {                        // q: 64 float4s
        int r  = tid >> 3;
        int u4 = (tid & 7) * 4;
        float4 v = *(const float4*)&qbuf[(size_t)(b * TT + t0 + r) * UU + u4];
        *(float4*)&q_sh[r][u4] = v;
    }
    if (tid < UU) wa_sh[tid] = Wa[tid];
    for (int p = tid; p < TCH * NS_MAX; p += 256) ((float*)a_sh)[p] = 0.f;
    float ba0 = ba[0];
    __syncthreads();

    // ---- phase 2: logits + softmax, one full wave per row ----
#pragma unroll
    for (int i = 0; i < TCH / 4; ++i) {
        int tl = w + 4 * i;               // local row (uniform per wave)
        int tg = t0 + tl;                 // global t
        int s  = tg - HALF_W + lane;      // this lane's source position
        float e = -1e30f;
        if (s >= 0 && s < TT) {
            int kr = s - bs0;             // consecutive per lane: conflict-free
            float acc = 0.f;
#pragma unroll
            for (int u = 0; u < UU; ++u)
                acc += fast_tanh(q_sh[tl][u] + k_sh[kr][u]) * wa_sh[u];
            e = acc + ba0;
        }
        float m = e;
#pragma unroll
        for (int off = 1; off < 64; off <<= 1) m = fmaxf(m, __shfl_xor(m, off));
        float p = __expf(e - m);
        float sum = p;
#pragma unroll
        for (int off = 1; off < 64; off <<= 1) sum += __shfl_xor(sum, off);
        if (s >= 0 && s < TT) a_sh[tl][s - bs0] = p / sum;
    }
    __syncthreads();

    // ---- phase 3: PV — wave w owns rows tg0, tg0+1; lane owns feature quad ----
    int tg0 = t0 + 2 * w;
    int sw0 = max(0, tg0 - HALF_W);
    int sw1 = min(TT, tg0 + 1 + HALF_W);        // exclusive
    const float4* __restrict__ xb = (const float4*)(x + (size_t)b * TT * FF);
    const float* __restrict__ ar0 = a_sh[2 * w + 0];
    const float* __restrict__ ar1 = a_sh[2 * w + 1];
    float4 acc0 = {0.f, 0.f, 0.f, 0.f};
    float4 acc1 = acc0;
#pragma unroll 4
    for (int s = sw0; s < sw1; ++s) {
        float4 xv = xb[(size_t)s * (FF / 4) + lane];
        int so = s - bs0;
        float av0 = ar0[so], av1 = ar1[so];
        acc0.x = fmaf(av0, xv.x, acc0.x);
        acc0.y = fmaf(av0, xv.y, acc0.y);
        acc0.z = fmaf(av0, xv.z, acc0.z);
        acc0.w = fmaf(av0, xv.w, acc0.w);
        acc1.x = fmaf(av1, xv.x, acc1.x);
        acc1.y = fmaf(av1, xv.y, acc1.y);
        acc1.z = fmaf(av1, xv.z, acc1.z);
        acc1.w = fmaf(av1, xv.w, acc1.w);
    }
    float4* ob = (float4*)(out + (size_t)(b * TT + tg0) * FF);
    ob[0 * (FF / 4) + lane] = acc0;
    ob[1 * (FF / 4) + lane] = acc1;
}

// ---------------------------------------------------------------------------
// Fallback (only if ws too small): fully fused, recomputes k per block.
// ---------------------------------------------------------------------------
__global__ __launch_bounds__(256) void fused_kernel(
    const float* __restrict__ x, const float* __restrict__ Wt,
    const float* __restrict__ Wx, const float* __restrict__ bh,
    const float* __restrict__ Wa, const float* __restrict__ ba,
    float* __restrict__ out) {
    int row = blockIdx.x;
    int t = row & (TT - 1);
    int b = row >> 10;
    int tid = threadIdx.x;
    int s0 = max(0, t - HALF_W);
    int s1 = min(TT, t + HALF_W);
    int W_ = s1 - s0;

    __shared__ float ks[WMAX * UU];   // 8 KB
    __shared__ float q_sh[UU];
    __shared__ float wa_sh[UU];
    __shared__ float e_sh[WMAX];
    __shared__ float a_sh[WMAX];

    if (tid < UU) {
        const float* xr = x + (size_t)row * FF;
        float acc = 0.f;
        for (int f = 0; f < FF; ++f) acc = fmaf(xr[f], Wt[f * UU + tid], acc);
        q_sh[tid]  = acc + bh[tid];
        wa_sh[tid] = Wa[tid];
    }
    for (int p = tid; p < W_ * UU; p += 256) {
        int sl = p >> 5, u = p & 31;
        const float* xr = x + (size_t)(b * TT + s0 + sl) * FF;
        float acc = 0.f;
        for (int f = 0; f < FF; ++f) acc = fmaf(xr[f], Wx[f * UU + u], acc);
        ks[p] = acc;
    }
    __syncthreads();

    int sl = tid >> 2;
    int j  = tid & 3;
    float partial = 0.f;
    if (sl < W_) {
#pragma unroll
        for (int uu = 0; uu < 8; ++uu) {
            int u = j * 8 + uu;
            partial += fast_tanh(q_sh[u] + ks[sl * UU + u]) * wa_sh[u];
        }
    }
    partial += __shfl_xor(partial, 1);
    partial += __shfl_xor(partial, 2);
    if (j == 0) e_sh[sl] = (sl < W_) ? partial + ba[0] : -1e30f;
    __syncthreads();

    if (tid < 64) {
        float e = e_sh[tid];
        float m = e;
#pragma unroll
        for (int off = 1; off < 64; off <<= 1) m = fmaxf(m, __shfl_xor(m, off));
        float p = __expf(e - m);
        float sum = p;
#pragma unroll
        for (int off = 1; off < 64; off <<= 1) sum += __shfl_xor(sum, off);
        a_sh[tid] = p / sum;
    }
    __syncthreads();

    float acc = 0.f;
    const float* xb = x + (size_t)(b * TT + s0) * FF + tid;
    for (int k2 = 0; k2 < W_; ++k2)
        acc = fmaf(a_sh[k2], xb[(size_t)k2 * FF], acc);
    out[(size_t)row * FF + tid] = acc;
}

extern "C" void kernel_launch(void* const* d_in, const int* in_sizes, int n_in,
                              void* d_out, int out_size, void* d_ws, size_t ws_size,
                              hipStream_t stream) {
    const float* x  = (const float*)d_in[0];
    const float* Wt = (const float*)d_in[1];
    const float* Wx = (const float*)d_in[2];
    const float* bh = (const float*)d_in[3];
    const float* Wa = (const float*)d_in[4];
    const float* ba = (const float*)d_in[5];
    float* out = (float*)d_out;

    const size_t need = (size_t)2 * BB * TT * UU * sizeof(float);   // 1 MiB
    if (ws_size >= need) {
        float* qbuf = (float*)d_ws;
        float* kbuf = qbuf + (size_t)BB * TT * UU;
        qk_kernel<<<BB * TT / RB, 256, 0, stream>>>(x, Wt, Wx, bh, qbuf, kbuf);
        attn2_kernel<<<BB * (TT / TCH), 256, 0, stream>>>(x, qbuf, kbuf, Wa, ba, out);
    } else {
        fused_kernel<<<BB * TT, 256, 0, stream>>>(x, Wt, Wx, bh, Wa, ba, out);
    }
}